// Round 8
// baseline (525.153 us; speedup 1.0000x reference)
//
#include <hip/hip_runtime.h>
#include <hip/hip_fp16.h>
#include <stdint.h>

// x[16384,2048] f32, w[2048,2048] f32, bias[2048] f32, scalar scales.
// M=16384, N=2048, K=2048. Output f16 values stored as f32.
#define MDIM 16384
#define NDIM 2048
#define KDIM 2048

typedef __attribute__((ext_vector_type(4))) float f32x4;
typedef __attribute__((ext_vector_type(4))) int   i32x4;
typedef __attribute__((ext_vector_type(8))) int   i32x8;

// ---------------------------------------------------------------------------
// Bit-exact f32 -> e4m3fn (OCP) RTNE after clip to +-448.
// ---------------------------------------------------------------------------
__device__ __forceinline__ unsigned f32_to_e4m3(float x) {
    float q = fminf(448.f, fmaxf(-448.f, x));
    unsigned ub = __float_as_uint(q);
    unsigned sgn = (ub >> 24) & 0x80u;
    float aq = fabsf(q);
    int E = (int)((__float_as_uint(aq) >> 23) & 0xff) - 127;
    if (E < -6) E = -6;
    float rq = __uint_as_float((unsigned)(130 - E) << 23);  // 2^(3-E), exact
    int m = (int)rintf(aq * rq);                            // RTNE, exact scale
    if (m == 16) { m = 8; E += 1; }
    unsigned bits;
    if (m < 8) bits = sgn | (unsigned)m;
    else       bits = sgn | ((unsigned)(E + 7) << 3) | (unsigned)(m - 8);
    return bits;
}

// x-quant: linear layout.  w-quant: fragment-major packed layout Bp:
//   block (n16 = col>>4, kb = ktile) of 2048B holds, at lane*32 (lane =
//   g*16 + r15), bytes w[n16*16+r15][kb*128 + g*32 .. +31].  A wave's bf
//   load of fragment n is then 64 lanes x 32B fully dense (zero line
//   inflation; B bypasses LDS entirely in the GEMM).
__global__ void quant_both_kernel(const float* __restrict__ x,
                                  uint8_t* __restrict__ xq,
                                  const float* __restrict__ w,
                                  uint8_t* __restrict__ wq,
                                  const float* __restrict__ s_in,
                                  const float* __restrict__ s_w) {
    if (blockIdx.x < 2048) {
        float sc = s_in[0];
        unsigned n16 = (unsigned)((size_t)MDIM * KDIM / 16);
        unsigned i = blockIdx.x * 256 + threadIdx.x;
        for (; i < n16; i += 2048 * 256) {
            const float4* xp = (const float4*)(x + (size_t)i * 16);
            uint32_t wd[4];
#pragma unroll
            for (int j = 0; j < 4; ++j) {
                float4 v = xp[j];
                wd[j] = f32_to_e4m3(v.x / sc) | (f32_to_e4m3(v.y / sc) << 8) |
                        (f32_to_e4m3(v.z / sc) << 16) | (f32_to_e4m3(v.w / sc) << 24);
            }
            ((uint4*)xq)[i] = make_uint4(wd[0], wd[1], wd[2], wd[3]);
        }
    } else {
        float sc = s_w[0];
        unsigned n16 = (unsigned)((size_t)NDIM * KDIM / 16);
        unsigned i = (blockIdx.x - 2048) * 256 + threadIdx.x;
        for (; i < n16; i += 256 * 256) {
            const float4* xp = (const float4*)(w + (size_t)i * 16);
            uint32_t wd[4];
#pragma unroll
            for (int j = 0; j < 4; ++j) {
                float4 v = xp[j];
                wd[j] = f32_to_e4m3(v.x / sc) | (f32_to_e4m3(v.y / sc) << 8) |
                        (f32_to_e4m3(v.z / sc) << 16) | (f32_to_e4m3(v.w / sc) << 24);
            }
            unsigned r = i >> 7, kc = i & 127;
            unsigned idx = ((r >> 4) * 16 + (kc >> 3)) * 128 +
                           ((kc & 7) >> 1) * 32 + (r & 15) * 2 + (kc & 1);
            ((uint4*)wq)[idx] = make_uint4(wd[0], wd[1], wd[2], wd[3]);
        }
    }
}

// ---------------------------------------------------------------------------
// GEMM: C = Aq * Bp^T via mfma_scale_f32_16x16x128_f8f6f4 (unit scales).
// 256x256 tile, BK=128B, 16 K-tiles, 8 waves (2Mx4N; per-wave 128x64).
//
// Round-8 structure: B DIRECT global->reg (packed layout, ping-pong bfA/bfB,
// full-tile L2-latency cover); A via LDS dbuf 2x32KiB only.  Per-CU-tile:
// LDS reads 128KiB (~1540cy) < MFMA 2210cy; L2 supply 96KiB (~1714cy).
// One barrier/tile; af0(t+1) pre-read overlaps mh1(t) MFMAs; af1(t) read
// overlaps mh0(t) MFMAs.  Counted vmcnt only (audited FIFO: issue order per
// tile = [... S(t+1) from t-1][G(t+1)][S(t+2)]):
//   step1 vmcnt(4): drains G(t)   -> bf(t) ready   (leaves S(t+1))
//   step6 vmcnt(8): drains S(t+1) -> buf(t+1) ready (leaves G(t+1))
// lgkmcnt(0) before each barrier: my buf[t] ds_reads serviced before any
// wave's S(t+2) DMA writes can land (WAR guard).
//
// A chunk swizzle per 128B row: phys = (c+row)&7, linear gload_lds dest,
// inverse on global src (dense: each wave-load covers 8 full rows), same
// perm on af reads (perm const: row stride 16 == 0 mod 8) -> 2-way residual.
// ---------------------------------------------------------------------------
#define BM 256
#define BN 256
#define BKB 128
#define NKT (KDIM / BKB)   // 16

__device__ __forceinline__ void gload_lds16(const uint8_t* g, uint8_t* l) {
    __builtin_amdgcn_global_load_lds(
        (const __attribute__((address_space(1))) void*)g,
        (__attribute__((address_space(3))) void*)l, 16, 0, 0);
}

__device__ __forceinline__ void barrier_fenced() {
    asm volatile("" ::: "memory");
    __builtin_amdgcn_s_barrier();
    asm volatile("" ::: "memory");
}

__global__ __launch_bounds__(512) void gemm_fp8_kernel(
    const uint8_t* __restrict__ Aq, const uint8_t* __restrict__ Bp,
    const float* __restrict__ bias, const float* __restrict__ s_in,
    const float* __restrict__ s_w, float* __restrict__ out) {

    extern __shared__ uint8_t lds[];   // 65536 B: 2 x 32KiB A-buf / f32[64][256]

    // XCD-aware bijective swizzle (nwg = 512, divisible by 8)
    int nwg = gridDim.x;
    int cpx = nwg >> 3;
    int bid = blockIdx.x;
    int swz = (bid & 7) * cpx + (bid >> 3);
    int tm = swz >> 3;                 // tiles_n = 8
    int tn = swz & 7;
    int row0 = tm * BM;
    int col0 = tn * BN;

    int tid  = threadIdx.x;
    int lane = tid & 63;
    int wid  = tid >> 6;
    int wr = wid >> 2, wc = wid & 3;   // 2M x 4N
    int r15 = lane & 15;
    int g   = lane >> 4;

    // af-read swizzle (row-invariant: all af rows == r15 mod 8... row%8 = r15%8)
    int perm0 = ((2 * g + r15) & 7) << 4;
    int perm1 = ((2 * g + 1 + r15) & 7) << 4;

    // ---- A staging: 2048 chunks/tile, 4 per thread, dense 8-chunk rows ----
    size_t ssrc[4]; int sdst[4];
#pragma unroll
    for (int i = 0; i < 4; ++i) {
        int p = i * 512 + tid;
        int lrow = p >> 3, pc = p & 7;
        int c = (pc - lrow) & 7;
        ssrc[i] = (size_t)lrow * KDIM + c * 16;
        sdst[i] = p * 16;
    }
    const uint8_t* Asrc = Aq + (size_t)row0 * KDIM;

#define STAGE(KT, BUF)                                                        \
    {                                                                         \
        _Pragma("unroll")                                                     \
        for (int j_ = 0; j_ < 4; ++j_)                                        \
            gload_lds16(Asrc + ssrc[j_] + (size_t)(KT) * BKB, (BUF) + sdst[j_]); \
    }

    // ---- B fragment base pointers (packed layout) ----
    const uint8_t* bfbase[4];
#pragma unroll
    for (int n = 0; n < 4; ++n) {
        int n16g = tn * 16 + wc * 4 + n;
        bfbase[n] = Bp + (size_t)(n16g * 16) * 2048 + lane * 32;
    }

#define LOAD_BF_G(DST, KT)                                                    \
    {                                                                         \
        _Pragma("unroll")                                                     \
        for (int n_ = 0; n_ < 4; ++n_) {                                      \
            const uint8_t* p_ = bfbase[n_] + (size_t)(KT) * 2048;             \
            i32x4 lo = *(const i32x4*)p_;                                     \
            i32x4 hi = *(const i32x4*)(p_ + 16);                              \
            _Pragma("unroll")                                                 \
            for (int q_ = 0; q_ < 4; ++q_) { DST[n_][q_] = lo[q_]; DST[n_][4 + q_] = hi[q_]; } \
        }                                                                     \
    }

    int aRowByte = (wr * 128 + r15) * 128;   // + MH*64*128 + m*16*128

#define LOAD_AF(BUF, MH)                                                      \
    {                                                                         \
        _Pragma("unroll")                                                     \
        for (int m_ = 0; m_ < 4; ++m_) {                                      \
            const uint8_t* rp = (BUF) + aRowByte + ((MH) * 64 + m_ * 16) * 128; \
            i32x4 lo = *(const i32x4*)(rp + perm0);                           \
            i32x4 hi = *(const i32x4*)(rp + perm1);                           \
            _Pragma("unroll")                                                 \
            for (int q_ = 0; q_ < 4; ++q_) { af[m_][q_] = lo[q_]; af[m_][4 + q_] = hi[q_]; } \
        }                                                                     \
    }

#define MFMA_HALF(MH, BF)                                                     \
    __builtin_amdgcn_s_setprio(1);                                            \
    _Pragma("unroll")                                                         \
    for (int m_ = 0; m_ < 4; ++m_)                                            \
        _Pragma("unroll")                                                     \
        for (int n_ = 0; n_ < 4; ++n_)                                        \
            acc[(MH) * 4 + m_][n_] =                                          \
                __builtin_amdgcn_mfma_scale_f32_16x16x128_f8f6f4(             \
                    af[m_], BF[n_], acc[(MH) * 4 + m_][n_],                   \
                    0, 0, 0, 127, 0, 127);                                    \
    __builtin_amdgcn_s_setprio(0);

    f32x4 acc[8][4];
#pragma unroll
    for (int m = 0; m < 8; ++m)
#pragma unroll
        for (int n = 0; n < 4; ++n)
            acc[m][n] = (f32x4){0.f, 0.f, 0.f, 0.f};

    i32x8 af[4], bfA[4], bfB[4];

    uint8_t* buf0 = &lds[0];
    uint8_t* buf1 = &lds[32768];

    // ---- prologue: S(0), G(0)->bfA, S(1); wait S(0); pre-read af0(0) ----
    STAGE(0, buf0);
    LOAD_BF_G(bfA, 0);
    STAGE(1, buf1);
    asm volatile("s_waitcnt vmcnt(12)" ::: "memory");
    barrier_fenced();
    LOAD_AF(buf0, 0);

#define TILE_BODY(T, BFC, BFN)                                                \
    {                                                                         \
        uint8_t* curbuf = ((T) & 1) ? buf1 : buf0;                            \
        uint8_t* nxtbuf = ((T) & 1) ? buf0 : buf1;                            \
        if ((T) + 1 < NKT) asm volatile("s_waitcnt vmcnt(4)" ::: "memory");   \
        else               asm volatile("s_waitcnt vmcnt(0)" ::: "memory");   \
        MFMA_HALF(0, BFC);                     /* af0(T) x bf(T) */           \
        LOAD_AF(curbuf, 1);                    /* af1(T), overlaps mh0 */     \
        if ((T) + 1 < NKT) LOAD_BF_G(BFN, (T) + 1);                           \
        asm volatile("s_waitcnt lgkmcnt(0)" ::: "memory");                    \
        if ((T) + 1 < NKT) asm volatile("s_waitcnt vmcnt(8)" ::: "memory");   \
        else               asm volatile("s_waitcnt vmcnt(0)" ::: "memory");   \
        barrier_fenced();                                                     \
        if ((T) + 2 < NKT) STAGE((T) + 2, curbuf);                            \
        MFMA_HALF(1, BFC);                     /* af1(T) x bf(T) */           \
        if ((T) + 1 < NKT) LOAD_AF(nxtbuf, 0); /* af0(T+1), overlaps mh1 */   \
    }

    for (int t = 0; t < NKT; t += 2) {
        TILE_BODY(t, bfA, bfB);
        TILE_BODY(t + 1, bfB, bfA);
    }

    // ---- epilogue: f16 double-round + bias; 64KiB slab, 4 passes ----
    barrier_fenced();
    float s = s_in[0] * s_w[0];
    float* slab = (float*)lds;               // f32[64][256]
    __half hb[4];
#pragma unroll
    for (int n = 0; n < 4; ++n)
        hb[n] = __float2half(bias[col0 + wc * 64 + n * 16 + r15]);

#pragma unroll
    for (int q = 0; q < 4; ++q) {            // q -> rows [q*64, q*64+64)
        if (wr == (q >> 1)) {
            const int mh = q & 1;
#pragma unroll
            for (int n = 0; n < 4; ++n) {
                int colb = wc * 64 + n * 16 + r15;
#pragma unroll
                for (int m = 0; m < 4; ++m) {
                    int sr = m * 16 + g * 4;
#pragma unroll
                    for (int r = 0; r < 4; ++r) {
                        __half h = __float2half(acc[mh * 4 + m][n][r] * s);
                        slab[(sr + r) * 256 + colb] = __half2float(__hadd(h, hb[n]));
                    }
                }
            }
        }
        barrier_fenced();
#pragma unroll
        for (int it = 0; it < 8; ++it) {
            int srow = wid * 8 + it;
            f32x4 vv = *(const f32x4*)&slab[srow * 256 + lane * 4];
            int grow = row0 + q * 64 + srow;
            *(f32x4*)&out[(size_t)grow * NDIM + col0 + lane * 4] = vv;
        }
        barrier_fenced();
    }
#undef STAGE
#undef LOAD_BF_G
#undef LOAD_AF
#undef MFMA_HALF
#undef TILE_BODY
}

// ---------------------------------------------------------------------------
extern "C" void kernel_launch(void* const* d_in, const int* in_sizes, int n_in,
                              void* d_out, int out_size, void* d_ws, size_t ws_size,
                              hipStream_t stream) {
    const float* x      = (const float*)d_in[0];   // [16384, 2048]
    const float* weight = (const float*)d_in[1];   // [2048, 2048]
    const float* bias   = (const float*)d_in[2];   // [2048]
    const float* s_in   = (const float*)d_in[3];   // [1]
    const float* s_w    = (const float*)d_in[4];   // [1]
    float* out          = (float*)d_out;

    uint8_t* xq = (uint8_t*)d_ws;                          // 33.5 MB (linear)
    uint8_t* wq = (uint8_t*)d_ws + (size_t)MDIM * KDIM;    // 4.2 MB (packed)

    quant_both_kernel<<<2304, 256, 0, stream>>>(x, xq, weight, wq, s_in, s_w);

    dim3 grid((MDIM / BM) * (NDIM / BN));   // 64 * 8 = 512
    gemm_fp8_kernel<<<grid, 512, 65536, stream>>>(xq, wq, bias, s_in, s_w, out);
}

// Round 9
// 126.856 us; speedup vs baseline: 4.1398x; 4.1398x over previous
//
#include <hip/hip_runtime.h>
#include <hip/hip_fp16.h>
#include <stdint.h>

// x[16384,2048] f32, w[2048,2048] f32, bias[2048] f32, scalar scales.
// M=16384, N=2048, K=2048. Output f16 values stored as f32.
#define MDIM 16384
#define NDIM 2048
#define KDIM 2048

typedef __attribute__((ext_vector_type(4))) float f32x4;
typedef __attribute__((ext_vector_type(4))) int   i32x4;
typedef __attribute__((ext_vector_type(8))) int   i32x8;

// ---------------------------------------------------------------------------
// Bit-exact f32 -> e4m3fn (OCP) RTNE after clip to +-448.
// ---------------------------------------------------------------------------
__device__ __forceinline__ unsigned f32_to_e4m3(float x) {
    float q = fminf(448.f, fmaxf(-448.f, x));
    unsigned ub = __float_as_uint(q);
    unsigned sgn = (ub >> 24) & 0x80u;
    float aq = fabsf(q);
    int E = (int)((__float_as_uint(aq) >> 23) & 0xff) - 127;
    if (E < -6) E = -6;
    float rq = __uint_as_float((unsigned)(130 - E) << 23);  // 2^(3-E), exact
    int m = (int)rintf(aq * rq);                            // RTNE, exact scale
    if (m == 16) { m = 8; E += 1; }
    unsigned bits;
    if (m < 8) bits = sgn | (unsigned)m;
    else       bits = sgn | ((unsigned)(E + 7) << 3) | (unsigned)(m - 8);
    return bits;
}

__device__ __forceinline__ void quant_span(const float* __restrict__ x,
                                           uint8_t* __restrict__ q, float sc,
                                           unsigned i0, unsigned stride,
                                           unsigned n16) {
    for (unsigned i = i0; i < n16; i += stride) {
        const float4* xp = (const float4*)(x + (size_t)i * 16);
        uint32_t w[4];
#pragma unroll
        for (int j = 0; j < 4; ++j) {
            float4 v = xp[j];
            w[j] = f32_to_e4m3(v.x / sc) | (f32_to_e4m3(v.y / sc) << 8) |
                   (f32_to_e4m3(v.z / sc) << 16) | (f32_to_e4m3(v.w / sc) << 24);
        }
        ((uint4*)q)[i] = make_uint4(w[0], w[1], w[2], w[3]);
    }
}

// Single dispatch: blocks [0,2048) quantize x, [2048,2304) quantize w.
__global__ void quant_both_kernel(const float* __restrict__ x,
                                  uint8_t* __restrict__ xq,
                                  const float* __restrict__ w,
                                  uint8_t* __restrict__ wq,
                                  const float* __restrict__ s_in,
                                  const float* __restrict__ s_w) {
    if (blockIdx.x < 2048) {
        unsigned i0 = blockIdx.x * 256 + threadIdx.x;
        quant_span(x, xq, s_in[0], i0, 2048 * 256,
                   (unsigned)((size_t)MDIM * KDIM / 16));
    } else {
        unsigned i0 = (blockIdx.x - 2048) * 256 + threadIdx.x;
        quant_span(w, wq, s_w[0], i0, 256 * 256,
                   (unsigned)((size_t)NDIM * KDIM / 16));
    }
}

// ---------------------------------------------------------------------------
// GEMM: C = Aq * Bq^T, fp8 e4m3, mfma_scale_f32_16x16x128_f8f6f4 (unit
// scales: exact, 2x fp8 rate, 32 contiguous K-bytes/lane; proven r4-r7).
//
// m201-faithful 4-phase cadence per K-tile (round-9): each phase =
//   { ds-reads for THIS phase's MFMAs ; stage ONE 16KB unit ;
//     s_barrier ; lgkmcnt(0) ; setprio(1) ; 8 MFMA ; setprio(0) ; s_barrier }
// Stage placement from unit-death analysis (all waves, barrier-ordered):
//   A-h0/A-h1 of buf dead after p2 -> stage A-h0(t+1)@p0(t), A-h1(t+1)@p1(t)
//     (other buffer, regions last read @p2(t-1): >=3 barriers margin)
//   B-h0/B-h1 of buf dead after p1 -> stage B-h0(t+2)@p2(t), B-h1(t+2)@p3(t)
//     (CURRENT buffer, regions last read @p1(t): >=1 barrier margin)
// One counted wait per tile at p3: vmcnt(4) (audited FIFO: at end-p3(t) the
// 4 loads newer than A-h1(t+1) are B(t+2); drains A(t+1),B(t+1)); tail
// t+2>=NKT uses vmcnt(0). Prologue: {A0,A1,B0,B1}(0), {B0,B1}(1), vmcnt(4).
// Buffer (64KB, per kt parity): A[256][128] @0, B[256][128] @32768;
// halves = 16KB units. Chunk swizzle per 128B row: phys=(c+row)&7, linear
// gload_lds dest, inverse on global src, same perm on reads (2-way residual).
// Frag regs af32+bf32=64 (r8 spill mode excluded).
// ---------------------------------------------------------------------------
#define BM 256
#define BN 256
#define BKB 128
#define NKT (KDIM / BKB)   // 16

__device__ __forceinline__ void gload_lds16(const uint8_t* g, uint8_t* l) {
    __builtin_amdgcn_global_load_lds(
        (const __attribute__((address_space(1))) void*)g,
        (__attribute__((address_space(3))) void*)l, 16, 0, 0);
}

__device__ __forceinline__ void barrier_raw() {
    asm volatile("" ::: "memory");
    __builtin_amdgcn_s_barrier();
    asm volatile("" ::: "memory");
}

__global__ __launch_bounds__(512) void gemm_fp8_kernel(
    const uint8_t* __restrict__ Aq, const uint8_t* __restrict__ Bq,
    const float* __restrict__ bias, const float* __restrict__ s_in,
    const float* __restrict__ s_w, float* __restrict__ out) {

    extern __shared__ uint8_t lds[];   // 131072 B: 2 x 64KiB kt-buffers

    // XCD-aware bijective swizzle (nwg = 512, divisible by 8)
    int nwg = gridDim.x;
    int cpx = nwg >> 3;
    int bid = blockIdx.x;
    int swz = (bid & 7) * cpx + (bid >> 3);
    int tm = swz >> 3;                 // tiles_n = 8
    int tn = swz & 7;
    int row0 = tm * BM;
    int col0 = tn * BN;

    int tid  = threadIdx.x;
    int lane = tid & 63;
    int wid  = tid >> 6;
    int wr = wid >> 2, wc = wid & 3;   // 2M x 4N
    int r15 = lane & 15;
    int g   = lane >> 4;

    // fragment-read swizzle offsets (bytes within a row's 8 chunks)
    int perm0 = ((2 * g + r15) & 7) << 4;
    int perm1 = ((2 * g + 1 + r15) & 7) << 4;

    // ---- unit staging coords: 1024 chunks (128 rows x 8), 2 per thread ----
    int up0 = tid, up1 = 512 + tid;
    int ur0 = up0 >> 3, uc0 = ((up0 & 7) - (ur0 & 7)) & 7;
    int ur1 = up1 >> 3, uc1 = ((up1 & 7) - (ur1 & 7)) & 7;

    const uint8_t* Asrc = Aq + (size_t)row0 * KDIM;
    const uint8_t* Bsrc = Bq + (size_t)col0 * KDIM;

    // MAT: 0 = A (buf offset 0), 1 = B (buf offset 32768). H: half 0/1.
#define STAGE_U(MAT, H, KT)                                                   \
    {                                                                         \
        uint8_t* dst_ = &lds[(((unsigned)(KT) & 1) << 16) + (MAT) * 32768 +   \
                             (H) * 16384];                                    \
        const uint8_t* src_ = (MAT) ? Bsrc : Asrc;                            \
        gload_lds16(src_ + (size_t)((H) * 128 + ur0) * KDIM +                 \
                        (size_t)(KT) * BKB + uc0 * 16,                        \
                    dst_ + up0 * 16);                                         \
        gload_lds16(src_ + (size_t)((H) * 128 + ur1) * KDIM +                 \
                        (size_t)(KT) * BKB + uc1 * 16,                        \
                    dst_ + up1 * 16);                                         \
    }

    f32x4 acc[8][4];
#pragma unroll
    for (int m = 0; m < 8; ++m)
#pragma unroll
        for (int n = 0; n < 4; ++n)
            acc[m][n] = (f32x4){0.f, 0.f, 0.f, 0.f};

    i32x8 af[4], bf[4];

    int aRow0 = wr * 128 + r15;                       // + MH*64 + m*16
    int bRow0 = (wc >> 1) * 128 + (wc & 1) * 64 + r15;  // + n*16

#define LOAD_AF(bo, MH)                                                       \
    _Pragma("unroll")                                                         \
    for (int m_ = 0; m_ < 4; ++m_) {                                          \
        const uint8_t* rp = lds + (bo) + (aRow0 + (MH) * 64 + m_ * 16) * 128; \
        i32x4 lo = *(const i32x4*)(rp + perm0);                               \
        i32x4 hi = *(const i32x4*)(rp + perm1);                               \
        _Pragma("unroll")                                                     \
        for (int q_ = 0; q_ < 4; ++q_) { af[m_][q_] = lo[q_]; af[m_][4 + q_] = hi[q_]; } \
    }

#define LOAD_BF2(bo, NH)                                                      \
    _Pragma("unroll")                                                         \
    for (int n_ = 2 * (NH); n_ < 2 * (NH) + 2; ++n_) {                        \
        const uint8_t* rp = lds + (bo) + 32768 + (bRow0 + n_ * 16) * 128;     \
        i32x4 lo = *(const i32x4*)(rp + perm0);                               \
        i32x4 hi = *(const i32x4*)(rp + perm1);                               \
        _Pragma("unroll")                                                     \
        for (int q_ = 0; q_ < 4; ++q_) { bf[n_][q_] = lo[q_]; bf[n_][4 + q_] = hi[q_]; } \
    }

#define MFMA8(MH, NH)                                                         \
    __builtin_amdgcn_s_setprio(1);                                            \
    _Pragma("unroll")                                                         \
    for (int m_ = 0; m_ < 4; ++m_)                                            \
        _Pragma("unroll")                                                     \
        for (int n_ = 2 * (NH); n_ < 2 * (NH) + 2; ++n_)                      \
            acc[(MH) * 4 + m_][n_] =                                          \
                __builtin_amdgcn_mfma_scale_f32_16x16x128_f8f6f4(             \
                    af[m_], bf[n_], acc[(MH) * 4 + m_][n_],                   \
                    0, 0, 0, 127, 0, 127);                                    \
    __builtin_amdgcn_s_setprio(0);

#define LGKM0 asm volatile("s_waitcnt lgkmcnt(0)" ::: "memory")

    // ---- prologue: kt0 all units + B(1); leave B(1) in flight ----
    STAGE_U(0, 0, 0); STAGE_U(0, 1, 0); STAGE_U(1, 0, 0); STAGE_U(1, 1, 0);
    STAGE_U(1, 0, 1); STAGE_U(1, 1, 1);
    asm volatile("s_waitcnt vmcnt(4)" ::: "memory");
    barrier_raw();

    for (int t = 0; t < NKT; ++t) {
        const unsigned bo = (unsigned)(t & 1) << 16;
        // ---- p0: af0-3(t), bf0-1(t); stage A-h0(t+1) ----
        LOAD_AF(bo, 0);
        LOAD_BF2(bo, 0);
        if (t + 1 < NKT) STAGE_U(0, 0, t + 1);
        barrier_raw(); LGKM0;
        MFMA8(0, 0);
        barrier_raw();
        // ---- p1: bf2-3(t); stage A-h1(t+1) ----
        LOAD_BF2(bo, 1);
        if (t + 1 < NKT) STAGE_U(0, 1, t + 1);
        barrier_raw(); LGKM0;
        MFMA8(0, 1);
        barrier_raw();
        // ---- p2: af4-7(t); stage B-h0(t+2) (current buf, B-h0 dead @p1) ----
        LOAD_AF(bo, 1);
        if (t + 2 < NKT) STAGE_U(1, 0, t + 2);
        barrier_raw(); LGKM0;
        MFMA8(1, 0);
        barrier_raw();
        // ---- p3: stage B-h1(t+2); counted wait ----
        if (t + 2 < NKT) STAGE_U(1, 1, t + 2);
        barrier_raw(); LGKM0;
        MFMA8(1, 1);
        if (t + 2 < NKT) asm volatile("s_waitcnt vmcnt(4)" ::: "memory");
        else             asm volatile("s_waitcnt vmcnt(0)" ::: "memory");
        barrier_raw();
    }

    // ---- epilogue: f16 double-round + bias; [128][256] f32 slab, 2 passes --
    float s = s_in[0] * s_w[0];
    float* slab = (float*)lds;
    __half hb[4];
#pragma unroll
    for (int n = 0; n < 4; ++n)
        hb[n] = __float2half(bias[col0 + wc * 64 + n * 16 + r15]);

#pragma unroll
    for (int mh = 0; mh < 2; ++mh) {
#pragma unroll
        for (int n = 0; n < 4; ++n) {
            int colb = wc * 64 + n * 16 + r15;
#pragma unroll
            for (int m = 0; m < 4; ++m) {
                int sr = wr * 64 + m * 16 + g * 4;
#pragma unroll
                for (int r = 0; r < 4; ++r) {
                    __half h = __float2half(acc[mh * 4 + m][n][r] * s);
                    slab[(sr + r) * 256 + colb] = __half2float(__hadd(h, hb[n]));
                }
            }
        }
        barrier_raw();
#pragma unroll
        for (int it = 0; it < 16; ++it) {
            int srow = wid * 16 + it;
            f32x4 vv = *(const f32x4*)&slab[srow * 256 + lane * 4];
            int grow = row0 + (srow >> 6) * 128 + mh * 64 + (srow & 63);
            *(f32x4*)&out[(size_t)grow * NDIM + col0 + lane * 4] = vv;
        }
        barrier_raw();
    }
#undef STAGE_U
#undef LOAD_AF
#undef LOAD_BF2
#undef MFMA8
#undef LGKM0
}

// ---------------------------------------------------------------------------
extern "C" void kernel_launch(void* const* d_in, const int* in_sizes, int n_in,
                              void* d_out, int out_size, void* d_ws, size_t ws_size,
                              hipStream_t stream) {
    const float* x      = (const float*)d_in[0];   // [16384, 2048]
    const float* weight = (const float*)d_in[1];   // [2048, 2048]
    const float* bias   = (const float*)d_in[2];   // [2048]
    const float* s_in   = (const float*)d_in[3];   // [1]
    const float* s_w    = (const float*)d_in[4];   // [1]
    float* out          = (float*)d_out;

    uint8_t* xq = (uint8_t*)d_ws;                          // 33.5 MB
    uint8_t* wq = (uint8_t*)d_ws + (size_t)MDIM * KDIM;    // 4.2 MB

    quant_both_kernel<<<2304, 256, 0, stream>>>(x, xq, weight, wq, s_in, s_w);

    dim3 grid((MDIM / BM) * (NDIM / BN));   // 64 * 8 = 512
    gemm_fp8_kernel<<<grid, 512, 131072, stream>>>(xq, wq, bias, s_in, s_w, out);
}